// Round 1
// baseline (281.689 us; speedup 1.0000x reference)
//
#include <hip/hip_runtime.h>
#include <math.h>

#define TAU_INV (1.0f / 0.07f)
#define KSEL 50
#define NPIX 8192
#define CCH 128
#define HWSZ 4096
#define NCLS 4
#define EPSL 1e-8f

// ---------------------------------------------------------------------------
// Kernel 1: per-pixel argmax(logits) for input & negative, and max softmax
// prob for negative.  argmax(softmax) == argmax(logits) (softmax monotone,
// first-max tie-break identical).  max prob = 1 / sum(exp(l - lmax)).
// ---------------------------------------------------------------------------
__global__ void seg_kernel(const float* __restrict__ ilog,
                           const float* __restrict__ nlog,
                           int* __restrict__ seg_in, int* __restrict__ seg_neg,
                           float* __restrict__ neg_prob) {
    int n = blockIdx.x * blockDim.x + threadIdx.x;
    if (n >= NPIX) return;
    int b = n >> 12, hw = n & (HWSZ - 1);

    const float* pi = ilog + (size_t)b * NCLS * HWSZ + hw;
    float l0 = pi[0], l1 = pi[HWSZ], l2 = pi[2 * HWSZ], l3 = pi[3 * HWSZ];
    int bi = 0; float bv = l0;
    if (l1 > bv) { bv = l1; bi = 1; }
    if (l2 > bv) { bv = l2; bi = 2; }
    if (l3 > bv) { bv = l3; bi = 3; }
    seg_in[n] = bi;

    const float* pn = nlog + (size_t)b * NCLS * HWSZ + hw;
    float m0 = pn[0], m1 = pn[HWSZ], m2 = pn[2 * HWSZ], m3 = pn[3 * HWSZ];
    int ci = 0; float cv = m0;
    if (m1 > cv) { cv = m1; ci = 1; }
    if (m2 > cv) { cv = m2; ci = 2; }
    if (m3 > cv) { cv = m3; ci = 3; }
    seg_neg[n] = ci;
    float s = expf(m0 - cv) + expf(m1 - cv) + expf(m2 - cv) + expf(m3 - cv);
    neg_prob[n] = 1.0f / s;
}

// ---------------------------------------------------------------------------
// Kernel 2: L2-normalize along C while transposing [B,C,H,W] -> [N,C].
// One block handles 64 consecutive pixels (same b) x all 128 channels.
// ---------------------------------------------------------------------------
__global__ void __launch_bounds__(256) norm_transpose(const float* __restrict__ src,
                                                      float* __restrict__ dst) {
    __shared__ float tile[CCH][65];   // stride 65: conflict-free both ways
    __shared__ float partial[4][64];
    __shared__ float invn[64];

    int t = threadIdx.x;
    int n0 = blockIdx.x * 64;
    int b = n0 >> 12, hw0 = n0 & (HWSZ - 1);
    const float* base = src + (size_t)b * CCH * HWSZ + hw0;

    // load: lanes sweep hw (coalesced), 32 elems/thread
    #pragma unroll
    for (int i = 0; i < 32; ++i) {
        int lin = t + i * 256;
        int c = lin >> 6, hw = lin & 63;
        tile[c][hw] = base[(size_t)c * HWSZ + hw];
    }
    __syncthreads();

    // norms: 4 partial-sums of 32 channels per pixel
    int nof = t & 63, part = t >> 6;
    float s = 0.f;
    #pragma unroll
    for (int j = 0; j < 32; ++j) {
        float v = tile[part * 32 + j][nof];
        s += v * v;
    }
    partial[part][nof] = s;
    __syncthreads();
    if (t < 64) {
        float tot = partial[0][t] + partial[1][t] + partial[2][t] + partial[3][t];
        invn[t] = 1.0f / fmaxf(sqrtf(tot), 1e-12f);
    }
    __syncthreads();

    // store: lanes sweep c (coalesced rows of [N,C])
    #pragma unroll
    for (int i = 0; i < 32; ++i) {
        int lin = t + i * 256;
        int nf = lin >> 7, c = lin & 127;
        dst[(size_t)(n0 + nf) * CCH + c] = tile[c][nf] * invn[nf];
    }
}

// ---------------------------------------------------------------------------
// Kernel 3: per-class top-50 of v_i = (seg_neg[i]!=c) ? neg_prob[i] : 0,
// ties -> lower index (matches jax.lax.top_k).  One block per class,
// values in LDS, 50 sequential argmax tree reductions.
// ---------------------------------------------------------------------------
__global__ void __launch_bounds__(256) topk_kernel(const int* __restrict__ seg_neg,
                                                   const float* __restrict__ neg_prob,
                                                   int* __restrict__ topk) {
    __shared__ float vals[NPIX];   // 32 KB
    __shared__ float rv[256];
    __shared__ int   ri[256];
    int c = blockIdx.x, t = threadIdx.x;

    for (int i = t; i < NPIX; i += 256)
        vals[i] = (seg_neg[i] != c) ? neg_prob[i] : 0.0f;
    __syncthreads();

    for (int k = 0; k < KSEL; ++k) {
        float bv = -2.0f; int bi = 0;
        for (int i = t; i < NPIX; i += 256) {
            float v = vals[i];
            if (v > bv) { bv = v; bi = i; }   // ascending i: keeps lowest idx
        }
        rv[t] = bv; ri[t] = bi;
        __syncthreads();
        for (int off = 128; off > 0; off >>= 1) {
            if (t < off) {
                float ov = rv[t + off]; int oi = ri[t + off];
                if (ov > rv[t] || (ov == rv[t] && oi < ri[t])) { rv[t] = ov; ri[t] = oi; }
            }
            __syncthreads();
        }
        if (t == 0) {
            topk[c * KSEL + k] = ri[0];
            vals[ri[0]] = -1.0f;   // remove from further selection
        }
        __syncthreads();
    }
}

// ---------------------------------------------------------------------------
// Kernel 4: per-pixel contrastive loss terms.  One wave per pixel; each lane
// holds 2 channels; dots via butterfly shuffles.  atomicAdd block partials.
// ---------------------------------------------------------------------------
__global__ void __launch_bounds__(256) loss_kernel(const float* __restrict__ ni,
                                                   const float* __restrict__ npos,
                                                   const float* __restrict__ nn,
                                                   const int* __restrict__ seg_in,
                                                   const int* __restrict__ topk,
                                                   float* __restrict__ acc) {
    __shared__ float bsum[4];
    int t = threadIdx.x;
    int lane = t & 63, w = t >> 6;
    int n = blockIdx.x * 4 + w;

    const float* rin = ni + (size_t)n * CCH;
    const float* rp  = npos + (size_t)n * CCH;
    float in0 = rin[lane], in1 = rin[lane + 64];
    float p0  = rp[lane],  p1  = rp[lane + 64];

    float ps = in0 * p0 + in1 * p1;
    #pragma unroll
    for (int off = 32; off; off >>= 1) ps += __shfl_xor(ps, off);

    int c = seg_in[n];
    const int* tk = topk + c * KSEL;

    float sum_i = 0.f, sum_p = 0.f;
    for (int k = 0; k < KSEL; ++k) {
        int idx = tk[k];
        const float* g = nn + (size_t)idx * CCH;
        float g0 = g[lane], g1 = g[lane + 64];
        float di = g0 * in0 + g1 * in1;
        float dp = g0 * p0 + g1 * p1;
        #pragma unroll
        for (int off = 32; off; off >>= 1) {
            di += __shfl_xor(di, off);
            dp += __shfl_xor(dp, off);
        }
        sum_i += expf(di * TAU_INV);
        sum_p += expf(dp * TAU_INV);
    }

    float nom = expf(ps * TAU_INV);
    float li = -logf(nom / (sum_i + nom + EPSL));
    float lp = -logf(nom / (sum_p + nom + EPSL));
    if (lane == 0) bsum[w] = li + lp;
    __syncthreads();
    if (t == 0) atomicAdd(acc, bsum[0] + bsum[1] + bsum[2] + bsum[3]);
}

__global__ void zero_kernel(float* __restrict__ acc) {
    if (threadIdx.x == 0) acc[0] = 0.0f;
}

__global__ void fin_kernel(const float* __restrict__ acc, float* __restrict__ out) {
    out[0] = acc[0] * (1.0f / (float)NPIX);
}

// ---------------------------------------------------------------------------
extern "C" void kernel_launch(void* const* d_in, const int* in_sizes, int n_in,
                              void* d_out, int out_size, void* d_ws, size_t ws_size,
                              hipStream_t stream) {
    const float* input      = (const float*)d_in[0];
    const float* positive   = (const float*)d_in[1];
    const float* negative   = (const float*)d_in[2];
    const float* in_logits  = (const float*)d_in[3];
    const float* neg_logits = (const float*)d_in[4];
    float* out = (float*)d_out;

    float* ws  = (float*)d_ws;
    float* ni  = ws;                       // [N*C]
    float* np_ = ws + 1048576;             // [N*C]
    float* nn  = ws + 2097152;             // [N*C]
    int*   seg_in   = (int*)(ws + 3145728);        // [N]
    int*   seg_neg  = seg_in + NPIX;               // [N]
    float* neg_prob = (float*)(seg_neg + NPIX);    // [N]
    int*   topk     = (int*)(neg_prob + NPIX);     // [4*50] (pad 256)
    float* acc      = (float*)(topk + 256);        // [1]

    zero_kernel<<<1, 64, 0, stream>>>(acc);
    seg_kernel<<<NPIX / 256, 256, 0, stream>>>(in_logits, neg_logits, seg_in, seg_neg, neg_prob);
    norm_transpose<<<NPIX / 64, 256, 0, stream>>>(input, ni);
    norm_transpose<<<NPIX / 64, 256, 0, stream>>>(positive, np_);
    norm_transpose<<<NPIX / 64, 256, 0, stream>>>(negative, nn);
    topk_kernel<<<NCLS, 256, 0, stream>>>(seg_neg, neg_prob, topk);
    loss_kernel<<<NPIX / 4, 256, 0, stream>>>(ni, np_, nn, seg_in, topk, acc);
    fin_kernel<<<1, 1, 0, stream>>>(acc, out);
}

// Round 2
// 149.159 us; speedup vs baseline: 1.8885x; 1.8885x over previous
//
#include <hip/hip_runtime.h>
#include <math.h>

#define TAU_INV (1.0f / 0.07f)
#define KSEL 50
#define NPIX 8192
#define CCH 128
#define HWSZ 4096
#define NCLS 4
#define EPSL 1e-8f
#define NBINS 1026   // bin 0 = masked/below 0.25; bins 1..1025 span [0.25, 1.0]

// ---------------------------------------------------------------------------
// Kernel 1: per-pixel argmax(logits) for input & negative, and max softmax
// prob for negative.  argmax(softmax) == argmax(logits).  Also zeroes acc.
// ---------------------------------------------------------------------------
__global__ void seg_kernel(const float* __restrict__ ilog,
                           const float* __restrict__ nlog,
                           int* __restrict__ seg_in, int* __restrict__ seg_neg,
                           float* __restrict__ neg_prob,
                           float* __restrict__ acc) {
    int n = blockIdx.x * blockDim.x + threadIdx.x;
    if (n == 0) acc[0] = 0.0f;
    if (n >= NPIX) return;
    int b = n >> 12, hw = n & (HWSZ - 1);

    const float* pi = ilog + (size_t)b * NCLS * HWSZ + hw;
    float l0 = pi[0], l1 = pi[HWSZ], l2 = pi[2 * HWSZ], l3 = pi[3 * HWSZ];
    int bi = 0; float bv = l0;
    if (l1 > bv) { bv = l1; bi = 1; }
    if (l2 > bv) { bv = l2; bi = 2; }
    if (l3 > bv) { bv = l3; bi = 3; }
    seg_in[n] = bi;

    const float* pn = nlog + (size_t)b * NCLS * HWSZ + hw;
    float m0 = pn[0], m1 = pn[HWSZ], m2 = pn[2 * HWSZ], m3 = pn[3 * HWSZ];
    int ci = 0; float cv = m0;
    if (m1 > cv) { cv = m1; ci = 1; }
    if (m2 > cv) { cv = m2; ci = 2; }
    if (m3 > cv) { cv = m3; ci = 3; }
    seg_neg[n] = ci;
    float s = expf(m0 - cv) + expf(m1 - cv) + expf(m2 - cv) + expf(m3 - cv);
    neg_prob[n] = 1.0f / s;
}

// ---------------------------------------------------------------------------
// Kernel 2: L2-normalize along C while transposing [B,C,H,W] -> [N,C].
// blockIdx.y selects which of the 3 tensors (fewer launches).
// ---------------------------------------------------------------------------
__global__ void __launch_bounds__(256) norm_transpose3(
        const float* __restrict__ s0, const float* __restrict__ s1,
        const float* __restrict__ s2,
        float* __restrict__ d0, float* __restrict__ d1, float* __restrict__ d2) {
    __shared__ float tile[CCH][65];
    __shared__ float partial[4][64];
    __shared__ float invn[64];

    const float* src = (blockIdx.y == 0) ? s0 : (blockIdx.y == 1) ? s1 : s2;
    float*       dst = (blockIdx.y == 0) ? d0 : (blockIdx.y == 1) ? d1 : d2;

    int t = threadIdx.x;
    int n0 = blockIdx.x * 64;
    int b = n0 >> 12, hw0 = n0 & (HWSZ - 1);
    const float* base = src + (size_t)b * CCH * HWSZ + hw0;

    #pragma unroll
    for (int i = 0; i < 32; ++i) {
        int lin = t + i * 256;
        int c = lin >> 6, hw = lin & 63;
        tile[c][hw] = base[(size_t)c * HWSZ + hw];
    }
    __syncthreads();

    int nof = t & 63, part = t >> 6;
    float s = 0.f;
    #pragma unroll
    for (int j = 0; j < 32; ++j) {
        float v = tile[part * 32 + j][nof];
        s += v * v;
    }
    partial[part][nof] = s;
    __syncthreads();
    if (t < 64) {
        float tot = partial[0][t] + partial[1][t] + partial[2][t] + partial[3][t];
        invn[t] = 1.0f / fmaxf(sqrtf(tot), 1e-12f);
    }
    __syncthreads();

    #pragma unroll
    for (int i = 0; i < 32; ++i) {
        int lin = t + i * 256;
        int nf = lin >> 7, c = lin & 127;
        dst[(size_t)(n0 + nf) * CCH + c] = tile[c][nf] * invn[nf];
    }
}

// ---------------------------------------------------------------------------
// Kernel 3: per-class top-50 via histogram select (2 passes, no 50x argmax).
// v_i = (seg_neg[i]!=c) ? neg_prob[i] : 0.  neg_prob in [0.25, 1.0] so its
// float bits lie in [0x3E800000, 0x3F800000] and are monotone in value.
// Output order within the 50 is irrelevant (loss sums over the set); the
// SELECTED SET matches jax.lax.top_k incl. tie->lowest-index semantics.
// ---------------------------------------------------------------------------
__global__ void __launch_bounds__(1024) topk_kernel(const int* __restrict__ seg_neg,
                                                    const float* __restrict__ neg_prob,
                                                    int* __restrict__ topk) {
    __shared__ unsigned hist[NBINS];
    __shared__ unsigned long long cand[2048];
    __shared__ unsigned above_cnt, cand_cnt;
    __shared__ int sB, sc0;

    int c = blockIdx.x, t = threadIdx.x;

    for (int i = t; i < NBINS; i += 1024) hist[i] = 0;
    if (t == 0) { above_cnt = 0; cand_cnt = 0; }
    __syncthreads();

    // Phase 1: histogram (keep keys/bins in registers for phase 3)
    unsigned keys[8]; int bins[8];
    #pragma unroll
    for (int s = 0; s < 8; ++s) {
        int i = t + s * 1024;
        float v = (seg_neg[i] != c) ? neg_prob[i] : 0.0f;
        unsigned key = __float_as_uint(v);
        int bin = (key < 0x3E800000u) ? 0 : (int)(1u + ((key - 0x3E800000u) >> 14));
        keys[s] = key; bins[s] = bin;
        atomicAdd(&hist[bin], 1u);
    }
    __syncthreads();

    // Phase 2: serial scan from the top to find boundary bin B
    if (t == 0) {
        unsigned cum = 0; int B = 0;
        for (int b = NBINS - 1; b >= 0; --b) {
            unsigned h = hist[b];
            if (cum + h >= KSEL) { B = b; break; }
            cum += h;
        }
        sB = B; sc0 = (int)cum;   // cum = count strictly above bin B (< 50)
    }
    __syncthreads();
    int B = sB, c0 = sc0;

    // Phase 3: emit definite winners; collect boundary-bin candidates
    #pragma unroll
    for (int s = 0; s < 8; ++s) {
        int i = t + s * 1024;
        if (bins[s] > B) {
            unsigned pos = atomicAdd(&above_cnt, 1u);
            topk[c * KSEL + pos] = i;
        } else if (bins[s] == B) {
            unsigned j = atomicAdd(&cand_cnt, 1u);
            if (j < 2048)  // statistically never exceeded (~6 avg per bin)
                cand[j] = ((unsigned long long)keys[s] << 32) |
                          (unsigned long long)(0xFFFFFFFFu - (unsigned)i);
        }
    }
    __syncthreads();

    // Phase 4: wave 0 picks the remaining (50 - c0) best boundary candidates.
    // Key packs (value desc, index asc) -> max-key == jax tie-break.
    int m = KSEL - c0;
    int cb = (int)cand_cnt; if (cb > 2048) cb = 2048;
    if (t < 64) {
        for (int r = 0; r < m; ++r) {
            unsigned long long best = 0;
            for (int j = t; j < cb; j += 64) {
                unsigned long long v = cand[j];
                if (v > best) best = v;
            }
            #pragma unroll
            for (int off = 32; off; off >>= 1) {
                unsigned long long o = __shfl_xor(best, off);
                if (o > best) best = o;
            }
            if (t == 0) topk[c * KSEL + c0 + r] = (int)(0xFFFFFFFFu - (unsigned)(best & 0xFFFFFFFFull));
            // clear the winner (keys are unique: idx embedded)
            for (int j = t; j < cb; j += 64)
                if (cand[j] == best) cand[j] = 0;
        }
    }
}

// ---------------------------------------------------------------------------
// Kernel 4: per-pixel contrastive loss terms (unchanged this round).
// ---------------------------------------------------------------------------
__global__ void __launch_bounds__(256) loss_kernel(const float* __restrict__ ni,
                                                   const float* __restrict__ npos,
                                                   const float* __restrict__ nn,
                                                   const int* __restrict__ seg_in,
                                                   const int* __restrict__ topk,
                                                   float* __restrict__ acc) {
    __shared__ float bsum[4];
    int t = threadIdx.x;
    int lane = t & 63, w = t >> 6;
    int n = blockIdx.x * 4 + w;

    const float* rin = ni + (size_t)n * CCH;
    const float* rp  = npos + (size_t)n * CCH;
    float in0 = rin[lane], in1 = rin[lane + 64];
    float p0  = rp[lane],  p1  = rp[lane + 64];

    float ps = in0 * p0 + in1 * p1;
    #pragma unroll
    for (int off = 32; off; off >>= 1) ps += __shfl_xor(ps, off);

    int c = seg_in[n];
    const int* tk = topk + c * KSEL;

    float sum_i = 0.f, sum_p = 0.f;
    for (int k = 0; k < KSEL; ++k) {
        int idx = tk[k];
        const float* g = nn + (size_t)idx * CCH;
        float g0 = g[lane], g1 = g[lane + 64];
        float di = g0 * in0 + g1 * in1;
        float dp = g0 * p0 + g1 * p1;
        #pragma unroll
        for (int off = 32; off; off >>= 1) {
            di += __shfl_xor(di, off);
            dp += __shfl_xor(dp, off);
        }
        sum_i += expf(di * TAU_INV);
        sum_p += expf(dp * TAU_INV);
    }

    float nom = expf(ps * TAU_INV);
    float li = -logf(nom / (sum_i + nom + EPSL));
    float lp = -logf(nom / (sum_p + nom + EPSL));
    if (lane == 0) bsum[w] = li + lp;
    __syncthreads();
    if (t == 0) atomicAdd(acc, bsum[0] + bsum[1] + bsum[2] + bsum[3]);
}

__global__ void fin_kernel(const float* __restrict__ acc, float* __restrict__ out) {
    out[0] = acc[0] * (1.0f / (float)NPIX);
}

// ---------------------------------------------------------------------------
extern "C" void kernel_launch(void* const* d_in, const int* in_sizes, int n_in,
                              void* d_out, int out_size, void* d_ws, size_t ws_size,
                              hipStream_t stream) {
    const float* input      = (const float*)d_in[0];
    const float* positive   = (const float*)d_in[1];
    const float* negative   = (const float*)d_in[2];
    const float* in_logits  = (const float*)d_in[3];
    const float* neg_logits = (const float*)d_in[4];
    float* out = (float*)d_out;

    float* ws  = (float*)d_ws;
    float* ni  = ws;                       // [N*C]
    float* np_ = ws + 1048576;             // [N*C]
    float* nn  = ws + 2097152;             // [N*C]
    int*   seg_in   = (int*)(ws + 3145728);        // [N]
    int*   seg_neg  = seg_in + NPIX;               // [N]
    float* neg_prob = (float*)(seg_neg + NPIX);    // [N]
    int*   topk     = (int*)(neg_prob + NPIX);     // [4*50] (pad 256)
    float* acc      = (float*)(topk + 256);        // [1]

    seg_kernel<<<NPIX / 256, 256, 0, stream>>>(in_logits, neg_logits, seg_in, seg_neg, neg_prob, acc);
    dim3 ngrid(NPIX / 64, 3);
    norm_transpose3<<<ngrid, 256, 0, stream>>>(input, positive, negative, ni, np_, nn);
    topk_kernel<<<NCLS, 1024, 0, stream>>>(seg_neg, neg_prob, topk);
    loss_kernel<<<NPIX / 4, 256, 0, stream>>>(ni, np_, nn, seg_in, topk, acc);
    fin_kernel<<<1, 1, 0, stream>>>(acc, out);
}

// Round 3
// 103.982 us; speedup vs baseline: 2.7090x; 1.4345x over previous
//
#include <hip/hip_runtime.h>
#include <math.h>

#define TAU_INV (1.0f / 0.07f)
#define KSEL 50
#define KPAD 64      // zero-padded rows 50..63: dot=0 -> exp=1 -> subtract 14
#define NPIX 8192
#define CCH 128
#define HWSZ 4096
#define NCLS 4
#define EPSL 1e-8f
#define NBINS 1026
#define PXT 16       // pixels per loss block
#define SROW 132     // LDS row stride in floats (2-way max bank aliasing = free)

// ---------------------------------------------------------------------------
// Kernel 0: zero the tiny accumulators (must precede atomics in mega kernel).
// ---------------------------------------------------------------------------
__global__ void init_kernel(float* __restrict__ acc, int* __restrict__ cnt) {
    if (threadIdx.x == 0) acc[0] = 0.0f;
    if (threadIdx.x < NCLS) cnt[threadIdx.x] = 0;
}

// ---------------------------------------------------------------------------
// Kernel 1 (mega): blocks 0..383 = L2-normalize+transpose the 3 tensors;
// blocks 384..415 = per-pixel argmax of logits + class bucketing.
// ---------------------------------------------------------------------------
__global__ void __launch_bounds__(256) mega_kernel(
        const float* __restrict__ input, const float* __restrict__ positive,
        const float* __restrict__ negative,
        const float* __restrict__ ilog, const float* __restrict__ nlog,
        float* __restrict__ ni, float* __restrict__ np_, float* __restrict__ nn,
        int* __restrict__ seg_neg, float* __restrict__ neg_prob,
        int* __restrict__ gcnt, int* __restrict__ perm) {
    __shared__ float tile[CCH][65];
    __shared__ float partial[4][64];
    __shared__ float invn[64];
    __shared__ int lcnt[NCLS], lbase[NCLS];

    int t = threadIdx.x;
    int blk = blockIdx.x;

    if (blk < 384) {
        // ---- norm+transpose path ----
        int tensor = blk >> 7, chunk = blk & 127;
        const float* src = (tensor == 0) ? input : (tensor == 1) ? positive : negative;
        float*       dst = (tensor == 0) ? ni    : (tensor == 1) ? np_      : nn;

        int n0 = chunk * 64;
        int b = n0 >> 12, hw0 = n0 & (HWSZ - 1);
        const float* base = src + (size_t)b * CCH * HWSZ + hw0;

        #pragma unroll
        for (int i = 0; i < 32; ++i) {
            int lin = t + i * 256;
            int c = lin >> 6, hw = lin & 63;
            tile[c][hw] = base[(size_t)c * HWSZ + hw];
        }
        __syncthreads();

        int nof = t & 63, part = t >> 6;
        float s = 0.f;
        #pragma unroll
        for (int j = 0; j < 32; ++j) {
            float v = tile[part * 32 + j][nof];
            s += v * v;
        }
        partial[part][nof] = s;
        __syncthreads();
        if (t < 64) {
            float tot = partial[0][t] + partial[1][t] + partial[2][t] + partial[3][t];
            invn[t] = 1.0f / fmaxf(sqrtf(tot), 1e-12f);
        }
        __syncthreads();

        #pragma unroll
        for (int i = 0; i < 32; ++i) {
            int lin = t + i * 256;
            int nf = lin >> 7, c = lin & 127;
            dst[(size_t)(n0 + nf) * CCH + c] = tile[c][nf] * invn[nf];
        }
    } else {
        // ---- seg + bucket path ----
        if (t < NCLS) lcnt[t] = 0;
        __syncthreads();

        int n = (blk - 384) * 256 + t;
        int b = n >> 12, hw = n & (HWSZ - 1);

        const float* pi = ilog + (size_t)b * NCLS * HWSZ + hw;
        float l0 = pi[0], l1 = pi[HWSZ], l2 = pi[2 * HWSZ], l3 = pi[3 * HWSZ];
        int bi = 0; float bv = l0;
        if (l1 > bv) { bv = l1; bi = 1; }
        if (l2 > bv) { bv = l2; bi = 2; }
        if (l3 > bv) { bv = l3; bi = 3; }

        const float* pn = nlog + (size_t)b * NCLS * HWSZ + hw;
        float m0 = pn[0], m1 = pn[HWSZ], m2 = pn[2 * HWSZ], m3 = pn[3 * HWSZ];
        int ci = 0; float cv = m0;
        if (m1 > cv) { cv = m1; ci = 1; }
        if (m2 > cv) { cv = m2; ci = 2; }
        if (m3 > cv) { cv = m3; ci = 3; }
        seg_neg[n] = ci;
        float s = expf(m0 - cv) + expf(m1 - cv) + expf(m2 - cv) + expf(m3 - cv);
        neg_prob[n] = 1.0f / s;

        int lpos = atomicAdd(&lcnt[bi], 1);
        __syncthreads();
        if (t < NCLS) lbase[t] = atomicAdd(&gcnt[t], lcnt[t]);
        __syncthreads();
        perm[bi * NPIX + lbase[bi] + lpos] = n;   // order within class is free
    }
}

// ---------------------------------------------------------------------------
// Kernel 2: per-class top-50 via histogram select (set == jax.lax.top_k set).
// ---------------------------------------------------------------------------
__global__ void __launch_bounds__(1024) topk_kernel(const int* __restrict__ seg_neg,
                                                    const float* __restrict__ neg_prob,
                                                    int* __restrict__ topk) {
    __shared__ unsigned hist[NBINS];
    __shared__ unsigned long long cand[2048];
    __shared__ unsigned above_cnt, cand_cnt;
    __shared__ int sB, sc0;

    int c = blockIdx.x, t = threadIdx.x;

    for (int i = t; i < NBINS; i += 1024) hist[i] = 0;
    if (t == 0) { above_cnt = 0; cand_cnt = 0; }
    __syncthreads();

    unsigned keys[8]; int bins[8];
    #pragma unroll
    for (int s = 0; s < 8; ++s) {
        int i = t + s * 1024;
        float v = (seg_neg[i] != c) ? neg_prob[i] : 0.0f;
        unsigned key = __float_as_uint(v);
        int bin = (key < 0x3E800000u) ? 0 : (int)(1u + ((key - 0x3E800000u) >> 14));
        keys[s] = key; bins[s] = bin;
        atomicAdd(&hist[bin], 1u);
    }
    __syncthreads();

    if (t == 0) {
        unsigned cum = 0; int B = 0;
        for (int b = NBINS - 1; b >= 0; --b) {
            unsigned h = hist[b];
            if (cum + h >= KSEL) { B = b; break; }
            cum += h;
        }
        sB = B; sc0 = (int)cum;
    }
    __syncthreads();
    int B = sB, c0 = sc0;

    #pragma unroll
    for (int s = 0; s < 8; ++s) {
        int i = t + s * 1024;
        if (bins[s] > B) {
            unsigned pos = atomicAdd(&above_cnt, 1u);
            topk[c * KSEL + pos] = i;
        } else if (bins[s] == B) {
            unsigned j = atomicAdd(&cand_cnt, 1u);
            if (j < 2048)
                cand[j] = ((unsigned long long)keys[s] << 32) |
                          (unsigned long long)(0xFFFFFFFFu - (unsigned)i);
        }
    }
    __syncthreads();

    int m = KSEL - c0;
    int cb = (int)cand_cnt; if (cb > 2048) cb = 2048;
    if (t < 64) {
        for (int r = 0; r < m; ++r) {
            unsigned long long best = 0;
            for (int j = t; j < cb; j += 64) {
                unsigned long long v = cand[j];
                if (v > best) best = v;
            }
            #pragma unroll
            for (int off = 32; off; off >>= 1) {
                unsigned long long o = __shfl_xor(best, off);
                if (o > best) best = o;
            }
            if (t == 0) topk[c * KSEL + c0 + r] = (int)(0xFFFFFFFFu - (unsigned)(best & 0xFFFFFFFFull));
            for (int j = t; j < cb; j += 64)
                if (cand[j] == best) cand[j] = 0;
        }
    }
}

// ---------------------------------------------------------------------------
// Kernel 3: same-class GEMM-style loss.  Block = 16 pixels of one class.
// S (50 rows zero-padded to 64), X, P staged in LDS (row stride 132 floats).
// Thread (ktid,pxid) owns 4 k-rows x 1 pixel x {input,positive}; dots fully
// accumulate in registers (no shuffles in inner loop).
// ---------------------------------------------------------------------------
__global__ void __launch_bounds__(256) loss_kernel(
        const float* __restrict__ ni, const float* __restrict__ npos,
        const float* __restrict__ nn, const int* __restrict__ topk,
        const int* __restrict__ perm, const int* __restrict__ cnt,
        float* __restrict__ acc) {
    __shared__ float Sl[KPAD * SROW];   // 33792 B
    __shared__ float Xl[PXT * SROW];    //  8448 B
    __shared__ float Pl[PXT * SROW];    //  8448 B
    __shared__ float bsum[4];

    int c = blockIdx.y;
    int count = cnt[c];
    int start = blockIdx.x * PXT;
    if (start >= count) return;
    int t = threadIdx.x;

    // stage S: 4 threads per row, 32 ch each
    {
        int row = t >> 2;
        int ch0 = (t & 3) * 32;
        float* dst = &Sl[row * SROW + ch0];
        if (row < KSEL) {
            const float* src = nn + (size_t)topk[c * KSEL + row] * CCH + ch0;
            #pragma unroll
            for (int i = 0; i < 8; ++i)
                ((float4*)dst)[i] = ((const float4*)src)[i];
        } else {
            float4 z = make_float4(0.f, 0.f, 0.f, 0.f);
            #pragma unroll
            for (int i = 0; i < 8; ++i)
                ((float4*)dst)[i] = z;
        }
    }
    // stage X, P: 16 threads per pixel row, 8 ch each
    {
        int row = t >> 4;
        int slot = start + row;
        int px = perm[c * NPIX + ((slot < count) ? slot : start)];
        int ch0 = (t & 15) * 8;
        const float* sx = ni + (size_t)px * CCH + ch0;
        const float* sp = npos + (size_t)px * CCH + ch0;
        float* dx = &Xl[row * SROW + ch0];
        float* dp = &Pl[row * SROW + ch0];
        ((float4*)dx)[0] = ((const float4*)sx)[0];
        ((float4*)dx)[1] = ((const float4*)sx)[1];
        ((float4*)dp)[0] = ((const float4*)sp)[0];
        ((float4*)dp)[1] = ((const float4*)sp)[1];
    }
    __syncthreads();

    int ktid = t & 15, pxid = t >> 4;
    float acc_i[4] = {0.f, 0.f, 0.f, 0.f};
    float acc_p[4] = {0.f, 0.f, 0.f, 0.f};
    float ps = 0.f;
    const float* Xr = &Xl[pxid * SROW];
    const float* Pr = &Pl[pxid * SROW];

    #pragma unroll 4
    for (int ch = 0; ch < CCH; ch += 4) {
        float4 xv = *(const float4*)&Xr[ch];
        float4 pv = *(const float4*)&Pr[ch];
        ps += xv.x * pv.x + xv.y * pv.y + xv.z * pv.z + xv.w * pv.w;
        #pragma unroll
        for (int r = 0; r < 4; ++r) {
            float4 sv = *(const float4*)&Sl[(ktid + r * 16) * SROW + ch];
            acc_i[r] += sv.x * xv.x + sv.y * xv.y + sv.z * xv.z + sv.w * xv.w;
            acc_p[r] += sv.x * pv.x + sv.y * pv.y + sv.z * pv.z + sv.w * pv.w;
        }
    }

    float si = 0.f, spp = 0.f;
    #pragma unroll
    for (int r = 0; r < 4; ++r) {
        si  += expf(acc_i[r] * TAU_INV);
        spp += expf(acc_p[r] * TAU_INV);
    }
    // reduce over the 16 ktid lanes (consecutive within the wave)
    #pragma unroll
    for (int off = 1; off < 16; off <<= 1) {
        si  += __shfl_xor(si, off);
        spp += __shfl_xor(spp, off);
    }

    float v = 0.f;
    if (ktid == 0 && (start + pxid) < count) {
        si  -= (float)(KPAD - KSEL);   // remove exp(0)=1 of the 14 zero rows
        spp -= (float)(KPAD - KSEL);
        float nom = expf(ps * TAU_INV);
        float li = -logf(nom / (si + nom + EPSL));
        float lp = -logf(nom / (spp + nom + EPSL));
        v = li + lp;
    }
    v += __shfl_xor(v, 16);
    v += __shfl_xor(v, 32);
    int w = t >> 6;
    if ((t & 63) == 0) bsum[w] = v;
    __syncthreads();
    if (t == 0) atomicAdd(acc, bsum[0] + bsum[1] + bsum[2] + bsum[3]);
}

__global__ void fin_kernel(const float* __restrict__ acc, float* __restrict__ out) {
    out[0] = acc[0] * (1.0f / (float)NPIX);
}

// ---------------------------------------------------------------------------
extern "C" void kernel_launch(void* const* d_in, const int* in_sizes, int n_in,
                              void* d_out, int out_size, void* d_ws, size_t ws_size,
                              hipStream_t stream) {
    const float* input      = (const float*)d_in[0];
    const float* positive   = (const float*)d_in[1];
    const float* negative   = (const float*)d_in[2];
    const float* in_logits  = (const float*)d_in[3];
    const float* neg_logits = (const float*)d_in[4];
    float* out = (float*)d_out;

    float* ws  = (float*)d_ws;
    float* ni  = ws;                               // [N*C]
    float* np_ = ws + 1048576;                     // [N*C]
    float* nn  = ws + 2097152;                     // [N*C]
    int*   seg_neg  = (int*)(ws + 3145728);        // [N]
    float* neg_prob = (float*)(seg_neg + NPIX);    // [N]
    int*   topk     = (int*)(neg_prob + NPIX);     // [4*50] (pad 256)
    int*   cnt      = topk + 256;                  // [4] (pad 64)
    float* acc      = (float*)(cnt + 64);          // [1] (pad 64)
    int*   perm     = (int*)(acc + 64);            // [4*N]

    init_kernel<<<1, 64, 0, stream>>>(acc, cnt);
    mega_kernel<<<416, 256, 0, stream>>>(input, positive, negative,
                                         in_logits, neg_logits,
                                         ni, np_, nn, seg_neg, neg_prob, cnt, perm);
    topk_kernel<<<NCLS, 1024, 0, stream>>>(seg_neg, neg_prob, topk);
    dim3 lgrid(NPIX / PXT, NCLS);
    loss_kernel<<<lgrid, 256, 0, stream>>>(ni, np_, nn, topk, perm, cnt, acc);
    fin_kernel<<<1, 1, 0, stream>>>(acc, out);
}

// Round 4
// 101.840 us; speedup vs baseline: 2.7660x; 1.0210x over previous
//
#include <hip/hip_runtime.h>
#include <math.h>

#define TAU_INV (1.0f / 0.07f)
#define KSEL 50
#define KPAD 64      // zero-padded rows 50..63: dot=0 -> exp=1 -> subtract 14
#define NPIX 8192
#define CCH 128
#define HWSZ 4096
#define NCLS 4
#define EPSL 1e-8f
#define NBINS 1026
#define PXT 16       // pixels per loss block
#define SROW 132     // LDS row stride in floats (2-way max bank aliasing = free)

// ---------------------------------------------------------------------------
// Kernel 1 (mega): blocks 0..383 = L2-normalize+transpose the 3 tensors;
// blocks 384..415 = per-pixel argmax of logits (input & negative class,
// negative max-softmax-prob).  No atomics, no bucketing here.
// ---------------------------------------------------------------------------
__global__ void __launch_bounds__(256) mega_kernel(
        const float* __restrict__ input, const float* __restrict__ positive,
        const float* __restrict__ negative,
        const float* __restrict__ ilog, const float* __restrict__ nlog,
        float* __restrict__ ni, float* __restrict__ np_, float* __restrict__ nn,
        int* __restrict__ seg_in, int* __restrict__ seg_neg,
        float* __restrict__ neg_prob) {
    __shared__ float tile[CCH][65];
    __shared__ float partial[4][64];
    __shared__ float invn[64];

    int t = threadIdx.x;
    int blk = blockIdx.x;

    if (blk < 384) {
        // ---- norm+transpose path ----
        int tensor = blk >> 7, chunk = blk & 127;
        const float* src = (tensor == 0) ? input : (tensor == 1) ? positive : negative;
        float*       dst = (tensor == 0) ? ni    : (tensor == 1) ? np_      : nn;

        int n0 = chunk * 64;
        int b = n0 >> 12, hw0 = n0 & (HWSZ - 1);
        const float* base = src + (size_t)b * CCH * HWSZ + hw0;

        #pragma unroll
        for (int i = 0; i < 32; ++i) {
            int lin = t + i * 256;
            int c = lin >> 6, hw = lin & 63;
            tile[c][hw] = base[(size_t)c * HWSZ + hw];
        }
        __syncthreads();

        int nof = t & 63, part = t >> 6;
        float s = 0.f;
        #pragma unroll
        for (int j = 0; j < 32; ++j) {
            float v = tile[part * 32 + j][nof];
            s += v * v;
        }
        partial[part][nof] = s;
        __syncthreads();
        if (t < 64) {
            float tot = partial[0][t] + partial[1][t] + partial[2][t] + partial[3][t];
            invn[t] = 1.0f / fmaxf(sqrtf(tot), 1e-12f);
        }
        __syncthreads();

        #pragma unroll
        for (int i = 0; i < 32; ++i) {
            int lin = t + i * 256;
            int nf = lin >> 7, c = lin & 127;
            dst[(size_t)(n0 + nf) * CCH + c] = tile[c][nf] * invn[nf];
        }
    } else {
        // ---- seg path ----
        int n = (blk - 384) * 256 + t;
        int b = n >> 12, hw = n & (HWSZ - 1);

        const float* pi = ilog + (size_t)b * NCLS * HWSZ + hw;
        float l0 = pi[0], l1 = pi[HWSZ], l2 = pi[2 * HWSZ], l3 = pi[3 * HWSZ];
        int bi = 0; float bv = l0;
        if (l1 > bv) { bv = l1; bi = 1; }
        if (l2 > bv) { bv = l2; bi = 2; }
        if (l3 > bv) { bv = l3; bi = 3; }
        seg_in[n] = bi;

        const float* pn = nlog + (size_t)b * NCLS * HWSZ + hw;
        float m0 = pn[0], m1 = pn[HWSZ], m2 = pn[2 * HWSZ], m3 = pn[3 * HWSZ];
        int ci = 0; float cv = m0;
        if (m1 > cv) { cv = m1; ci = 1; }
        if (m2 > cv) { cv = m2; ci = 2; }
        if (m3 > cv) { cv = m3; ci = 3; }
        seg_neg[n] = ci;
        float s = expf(m0 - cv) + expf(m1 - cv) + expf(m2 - cv) + expf(m3 - cv);
        neg_prob[n] = 1.0f / s;
    }
}

// ---------------------------------------------------------------------------
// Kernel 2: per class c (one block each):
//   (a) top-50 of (seg_neg!=c)*neg_prob via histogram select
//       (selected SET == jax.lax.top_k set incl. tie->lowest-index),
//   (b) bucket pixels with seg_in==c into perm[c] (LDS counter, no global
//       atomics -> nothing to pre-zero), cnt[c] plain store,
//   (c) block 0 zeroes d_out (loss accumulates into it next).
// Boundary-bin scan is two-level (33 coarse sums, then <=64 serial steps).
// ---------------------------------------------------------------------------
__global__ void __launch_bounds__(1024) topk_kernel(
        const int* __restrict__ seg_in, const int* __restrict__ seg_neg,
        const float* __restrict__ neg_prob,
        int* __restrict__ topk, int* __restrict__ perm, int* __restrict__ cnt,
        float* __restrict__ out) {
    __shared__ unsigned hist[NBINS];
    __shared__ unsigned coarse[33];
    __shared__ unsigned long long cand[2048];
    __shared__ unsigned above_cnt, cand_cnt, bucket_cnt;
    __shared__ int sB, sc0;

    int c = blockIdx.x, t = threadIdx.x;
    if (c == 0 && t == 0) out[0] = 0.0f;

    for (int i = t; i < NBINS; i += 1024) hist[i] = 0;
    if (t < 33) coarse[t] = 0;
    if (t == 0) { above_cnt = 0; cand_cnt = 0; bucket_cnt = 0; }
    __syncthreads();

    // Phase 1: histogram + same-class pixel bucketing
    unsigned keys[8]; int bins[8];
    #pragma unroll
    for (int s = 0; s < 8; ++s) {
        int i = t + s * 1024;
        float v = (seg_neg[i] != c) ? neg_prob[i] : 0.0f;
        unsigned key = __float_as_uint(v);
        int bin = (key < 0x3E800000u) ? 0 : (int)(1u + ((key - 0x3E800000u) >> 14));
        keys[s] = key; bins[s] = bin;
        atomicAdd(&hist[bin], 1u);
        if (seg_in[i] == c) {
            unsigned p = atomicAdd(&bucket_cnt, 1u);
            perm[c * NPIX + p] = i;   // order within class is free
        }
    }
    __syncthreads();
    if (t == 0) cnt[c] = (int)bucket_cnt;

    // Phase 2a: coarse sums (32 bins per chunk)
    for (int i = t; i < NBINS; i += 1024) atomicAdd(&coarse[i >> 5], hist[i]);
    __syncthreads();

    // Phase 2b: two-level serial scan from the top (<= 33+32 steps)
    if (t == 0) {
        unsigned cum = 0; int j = 32;
        for (; j > 0; --j) {
            unsigned h = coarse[j];
            if (cum + h >= KSEL) break;
            cum += h;
        }
        int hi = j * 32 + 31; if (hi > NBINS - 1) hi = NBINS - 1;
        int B = 0;
        for (int b = hi; b >= j * 32; --b) {
            unsigned h = hist[b];
            if (cum + h >= KSEL) { B = b; break; }
            cum += h;
        }
        sB = B; sc0 = (int)cum;   // cum = count strictly above bin B (< 50)
    }
    __syncthreads();
    int B = sB, c0 = sc0;

    // Phase 3: emit definite winners; collect boundary-bin candidates
    #pragma unroll
    for (int s = 0; s < 8; ++s) {
        int i = t + s * 1024;
        if (bins[s] > B) {
            unsigned pos = atomicAdd(&above_cnt, 1u);
            topk[c * KSEL + pos] = i;
        } else if (bins[s] == B) {
            unsigned j = atomicAdd(&cand_cnt, 1u);
            if (j < 2048)
                cand[j] = ((unsigned long long)keys[s] << 32) |
                          (unsigned long long)(0xFFFFFFFFu - (unsigned)i);
        }
    }
    __syncthreads();

    // Phase 4: wave 0 picks remaining (50 - c0) best boundary candidates.
    int m = KSEL - c0;
    int cb = (int)cand_cnt; if (cb > 2048) cb = 2048;
    if (t < 64) {
        for (int r = 0; r < m; ++r) {
            unsigned long long best = 0;
            for (int j = t; j < cb; j += 64) {
                unsigned long long v = cand[j];
                if (v > best) best = v;
            }
            #pragma unroll
            for (int off = 32; off; off >>= 1) {
                unsigned long long o = __shfl_xor(best, off);
                if (o > best) best = o;
            }
            if (t == 0) topk[c * KSEL + c0 + r] = (int)(0xFFFFFFFFu - (unsigned)(best & 0xFFFFFFFFull));
            for (int j = t; j < cb; j += 64)
                if (cand[j] == best) cand[j] = 0;
        }
    }
}

// ---------------------------------------------------------------------------
// Kernel 3: same-class GEMM-style loss.  Block = 16 pixels of one class.
// Accumulates (li+lp)/NPIX straight into d_out (zeroed by topk_kernel).
// ---------------------------------------------------------------------------
__global__ void __launch_bounds__(256) loss_kernel(
        const float* __restrict__ ni, const float* __restrict__ npos,
        const float* __restrict__ nn, const int* __restrict__ topk,
        const int* __restrict__ perm, const int* __restrict__ cnt,
        float* __restrict__ out) {
    __shared__ float Sl[KPAD * SROW];   // 33792 B
    __shared__ float Xl[PXT * SROW];    //  8448 B
    __shared__ float Pl[PXT * SROW];    //  8448 B
    __shared__ float bsum[4];

    int c = blockIdx.y;
    int count = cnt[c];
    int start = blockIdx.x * PXT;
    if (start >= count) return;
    int t = threadIdx.x;

    // stage S: 4 threads per row, 32 ch each
    {
        int row = t >> 2;
        int ch0 = (t & 3) * 32;
        float* dst = &Sl[row * SROW + ch0];
        if (row < KSEL) {
            const float* src = nn + (size_t)topk[c * KSEL + row] * CCH + ch0;
            #pragma unroll
            for (int i = 0; i < 8; ++i)
                ((float4*)dst)[i] = ((const float4*)src)[i];
        } else {
            float4 z = make_float4(0.f, 0.f, 0.f, 0.f);
            #pragma unroll
            for (int i = 0; i < 8; ++i)
                ((float4*)dst)[i] = z;
        }
    }
    // stage X, P: 16 threads per pixel row, 8 ch each
    {
        int row = t >> 4;
        int slot = start + row;
        int px = perm[c * NPIX + ((slot < count) ? slot : start)];
        int ch0 = (t & 15) * 8;
        const float* sx = ni + (size_t)px * CCH + ch0;
        const float* sp = npos + (size_t)px * CCH + ch0;
        float* dx = &Xl[row * SROW + ch0];
        float* dp = &Pl[row * SROW + ch0];
        ((float4*)dx)[0] = ((const float4*)sx)[0];
        ((float4*)dx)[1] = ((const float4*)sx)[1];
        ((float4*)dp)[0] = ((const float4*)sp)[0];
        ((float4*)dp)[1] = ((const float4*)sp)[1];
    }
    __syncthreads();

    int ktid = t & 15, pxid = t >> 4;
    float acc_i[4] = {0.f, 0.f, 0.f, 0.f};
    float acc_p[4] = {0.f, 0.f, 0.f, 0.f};
    float ps = 0.f;
    const float* Xr = &Xl[pxid * SROW];
    const float* Pr = &Pl[pxid * SROW];

    #pragma unroll 4
    for (int ch = 0; ch < CCH; ch += 4) {
        float4 xv = *(const float4*)&Xr[ch];
        float4 pv = *(const float4*)&Pr[ch];
        ps += xv.x * pv.x + xv.y * pv.y + xv.z * pv.z + xv.w * pv.w;
        #pragma unroll
        for (int r = 0; r < 4; ++r) {
            float4 sv = *(const float4*)&Sl[(ktid + r * 16) * SROW + ch];
            acc_i[r] += sv.x * xv.x + sv.y * xv.y + sv.z * xv.z + sv.w * xv.w;
            acc_p[r] += sv.x * pv.x + sv.y * pv.y + sv.z * pv.z + sv.w * pv.w;
        }
    }

    float si = 0.f, spp = 0.f;
    #pragma unroll
    for (int r = 0; r < 4; ++r) {
        si  += expf(acc_i[r] * TAU_INV);
        spp += expf(acc_p[r] * TAU_INV);
    }
    #pragma unroll
    for (int off = 1; off < 16; off <<= 1) {
        si  += __shfl_xor(si, off);
        spp += __shfl_xor(spp, off);
    }

    float v = 0.f;
    if (ktid == 0 && (start + pxid) < count) {
        si  -= (float)(KPAD - KSEL);   // remove exp(0)=1 of the 14 zero rows
        spp -= (float)(KPAD - KSEL);
        float nom = expf(ps * TAU_INV);
        float li = -logf(nom / (si + nom + EPSL));
        float lp = -logf(nom / (spp + nom + EPSL));
        v = (li + lp) * (1.0f / (float)NPIX);
    }
    v += __shfl_xor(v, 16);
    v += __shfl_xor(v, 32);
    int w = t >> 6;
    if ((t & 63) == 0) bsum[w] = v;
    __syncthreads();
    if (t == 0) atomicAdd(out, bsum[0] + bsum[1] + bsum[2] + bsum[3]);
}

// ---------------------------------------------------------------------------
extern "C" void kernel_launch(void* const* d_in, const int* in_sizes, int n_in,
                              void* d_out, int out_size, void* d_ws, size_t ws_size,
                              hipStream_t stream) {
    const float* input      = (const float*)d_in[0];
    const float* positive   = (const float*)d_in[1];
    const float* negative   = (const float*)d_in[2];
    const float* in_logits  = (const float*)d_in[3];
    const float* neg_logits = (const float*)d_in[4];
    float* out = (float*)d_out;

    float* ws  = (float*)d_ws;
    float* ni  = ws;                               // [N*C]
    float* np_ = ws + 1048576;                     // [N*C]
    float* nn  = ws + 2097152;                     // [N*C]
    int*   seg_in   = (int*)(ws + 3145728);        // [N]
    int*   seg_neg  = seg_in + NPIX;               // [N]
    float* neg_prob = (float*)(seg_neg + NPIX);    // [N]
    int*   topk     = (int*)(neg_prob + NPIX);     // [4*50] (pad 256)
    int*   cnt      = topk + 256;                  // [4] (pad 64)
    int*   perm     = cnt + 64;                    // [4*N]

    mega_kernel<<<416, 256, 0, stream>>>(input, positive, negative,
                                         in_logits, neg_logits,
                                         ni, np_, nn, seg_in, seg_neg, neg_prob);
    topk_kernel<<<NCLS, 1024, 0, stream>>>(seg_in, seg_neg, neg_prob,
                                           topk, perm, cnt, out);
    dim3 lgrid(NPIX / PXT, NCLS);
    loss_kernel<<<lgrid, 256, 0, stream>>>(ni, np_, nn, topk, perm, cnt, out);
}

// Round 5
// 99.712 us; speedup vs baseline: 2.8250x; 1.0213x over previous
//
#include <hip/hip_runtime.h>
#include <math.h>

#define TAU_INV (1.0f / 0.07f)
#define KSEL 50
#define KPAD 64      // zero-padded rows 50..63: dot=0 -> exp=1 -> subtract 14
#define NPIX 8192
#define CCH 128
#define HWSZ 4096
#define NCLS 4
#define EPSL 1e-8f
#define NBINS 1026
#define PXT 32       // pixels per loss block
#define SROW 132     // LDS row stride in floats

// ---------------------------------------------------------------------------
// Kernel 1 (mega): blocks 0..383 = L2-normalize+transpose the 3 tensors
// (float4 global traffic both directions); blocks 384..391 = seg path,
// 4 pixels/thread via float4.
// ---------------------------------------------------------------------------
__global__ void __launch_bounds__(256) mega_kernel(
        const float* __restrict__ input, const float* __restrict__ positive,
        const float* __restrict__ negative,
        const float* __restrict__ ilog, const float* __restrict__ nlog,
        float* __restrict__ ni, float* __restrict__ np_, float* __restrict__ nn,
        int* __restrict__ seg_in, int* __restrict__ seg_neg,
        float* __restrict__ neg_prob) {
    __shared__ float tile[CCH][65];   // stride 65: conflict-free col/row mix
    __shared__ float partial[4][64];
    __shared__ float invn[64];

    int t = threadIdx.x;
    int blk = blockIdx.x;

    if (blk < 384) {
        // ---- norm+transpose path ----
        int tensor = blk >> 7, chunk = blk & 127;
        const float* src = (tensor == 0) ? input : (tensor == 1) ? positive : negative;
        float*       dst = (tensor == 0) ? ni    : (tensor == 1) ? np_      : nn;

        int n0 = chunk * 64;
        int b = n0 >> 12, hw0 = n0 & (HWSZ - 1);
        const float* base = src + (size_t)b * CCH * HWSZ + hw0;

        // load: float4 along hw; 4 scalar LDS writes (conflict-free, stride 65)
        #pragma unroll
        for (int i = 0; i < 8; ++i) {
            int lin = t + i * 256;
            int c = lin >> 4, hwq = (lin & 15) * 4;
            float4 v = *(const float4*)&base[(size_t)c * HWSZ + hwq];
            tile[c][hwq + 0] = v.x; tile[c][hwq + 1] = v.y;
            tile[c][hwq + 2] = v.z; tile[c][hwq + 3] = v.w;
        }
        __syncthreads();

        int nof = t & 63, part = t >> 6;
        float s = 0.f;
        #pragma unroll
        for (int j = 0; j < 32; ++j) {
            float v = tile[part * 32 + j][nof];
            s += v * v;
        }
        partial[part][nof] = s;
        __syncthreads();
        if (t < 64) {
            float tot = partial[0][t] + partial[1][t] + partial[2][t] + partial[3][t];
            invn[t] = 1.0f / fmaxf(sqrtf(tot), 1e-12f);
        }
        __syncthreads();

        // store: gather 4 consecutive channels (4-way LDS conflict, cheap) ->
        // one float4 coalesced global store
        #pragma unroll
        for (int i = 0; i < 8; ++i) {
            int lin = t + i * 256;
            int nf = lin >> 5, cq = (lin & 31) * 4;
            float inv = invn[nf];
            float4 o;
            o.x = tile[cq + 0][nf] * inv;
            o.y = tile[cq + 1][nf] * inv;
            o.z = tile[cq + 2][nf] * inv;
            o.w = tile[cq + 3][nf] * inv;
            *(float4*)&dst[(size_t)(n0 + nf) * CCH + cq] = o;
        }
    } else {
        // ---- seg path: 4 consecutive pixels per thread ----
        int n0 = ((blk - 384) * 256 + t) * 4;
        int b = n0 >> 12, hw = n0 & (HWSZ - 1);

        const float* pi = ilog + (size_t)b * NCLS * HWSZ + hw;
        float4 a0 = *(const float4*)&pi[0];
        float4 a1 = *(const float4*)&pi[HWSZ];
        float4 a2 = *(const float4*)&pi[2 * HWSZ];
        float4 a3 = *(const float4*)&pi[3 * HWSZ];
        const float* pn = nlog + (size_t)b * NCLS * HWSZ + hw;
        float4 b0 = *(const float4*)&pn[0];
        float4 b1 = *(const float4*)&pn[HWSZ];
        float4 b2 = *(const float4*)&pn[2 * HWSZ];
        float4 b3 = *(const float4*)&pn[3 * HWSZ];

        int4 si4, sn4; float4 npb;
        const float* A0 = (const float*)&a0; const float* A1 = (const float*)&a1;
        const float* A2 = (const float*)&a2; const float* A3 = (const float*)&a3;
        const float* B0 = (const float*)&b0; const float* B1 = (const float*)&b1;
        const float* B2 = (const float*)&b2; const float* B3 = (const float*)&b3;
        int* SI = (int*)&si4; int* SN = (int*)&sn4; float* NP = (float*)&npb;
        #pragma unroll
        for (int j = 0; j < 4; ++j) {
            float l0 = A0[j], l1 = A1[j], l2 = A2[j], l3 = A3[j];
            int bi = 0; float bv = l0;
            if (l1 > bv) { bv = l1; bi = 1; }
            if (l2 > bv) { bv = l2; bi = 2; }
            if (l3 > bv) { bv = l3; bi = 3; }
            SI[j] = bi;
            float m0 = B0[j], m1 = B1[j], m2 = B2[j], m3 = B3[j];
            int ci = 0; float cv = m0;
            if (m1 > cv) { cv = m1; ci = 1; }
            if (m2 > cv) { cv = m2; ci = 2; }
            if (m3 > cv) { cv = m3; ci = 3; }
            SN[j] = ci;
            float s = expf(m0 - cv) + expf(m1 - cv) + expf(m2 - cv) + expf(m3 - cv);
            NP[j] = 1.0f / s;
        }
        *(int4*)&seg_in[n0] = si4;
        *(int4*)&seg_neg[n0] = sn4;
        *(float4*)&neg_prob[n0] = npb;
    }
}

// ---------------------------------------------------------------------------
// Kernel 2: per class c (one block each): top-50 histogram select +
// same-class pixel bucketing + out zeroing.  Vectorized phase-1 loads.
// ---------------------------------------------------------------------------
__global__ void __launch_bounds__(1024) topk_kernel(
        const int* __restrict__ seg_in, const int* __restrict__ seg_neg,
        const float* __restrict__ neg_prob,
        int* __restrict__ topk, int* __restrict__ perm, int* __restrict__ cnt,
        float* __restrict__ out) {
    __shared__ unsigned hist[NBINS];
    __shared__ unsigned coarse[33];
    __shared__ unsigned long long cand[2048];
    __shared__ unsigned above_cnt, cand_cnt, bucket_cnt;
    __shared__ int sB, sc0;

    int c = blockIdx.x, t = threadIdx.x;
    if (c == 0 && t == 0) out[0] = 0.0f;

    for (int i = t; i < NBINS; i += 1024) hist[i] = 0;
    if (t < 33) coarse[t] = 0;
    if (t == 0) { above_cnt = 0; cand_cnt = 0; bucket_cnt = 0; }
    __syncthreads();

    // Phase 1: histogram + same-class pixel bucketing (int4/float4 loads)
    unsigned keys[8]; int bins[8];
    #pragma unroll
    for (int s = 0; s < 2; ++s) {
        int i4 = (t + s * 1024) * 4;
        int4 sn = *(const int4*)&seg_neg[i4];
        int4 sg = *(const int4*)&seg_in[i4];
        float4 npv = *(const float4*)&neg_prob[i4];
        const int* SN = (const int*)&sn;
        const int* SG = (const int*)&sg;
        const float* NP = (const float*)&npv;
        #pragma unroll
        for (int j = 0; j < 4; ++j) {
            float v = (SN[j] != c) ? NP[j] : 0.0f;
            unsigned key = __float_as_uint(v);
            int bin = (key < 0x3E800000u) ? 0 : (int)(1u + ((key - 0x3E800000u) >> 14));
            keys[s * 4 + j] = key; bins[s * 4 + j] = bin;
            atomicAdd(&hist[bin], 1u);
            if (SG[j] == c) {
                unsigned p = atomicAdd(&bucket_cnt, 1u);
                perm[c * NPIX + p] = i4 + j;   // order within class is free
            }
        }
    }
    __syncthreads();
    if (t == 0) cnt[c] = (int)bucket_cnt;

    // Phase 2a: coarse sums (32 bins per chunk)
    for (int i = t; i < NBINS; i += 1024) atomicAdd(&coarse[i >> 5], hist[i]);
    __syncthreads();

    // Phase 2b: two-level serial scan from the top (<= 33+32 steps)
    if (t == 0) {
        unsigned cum = 0; int j = 32;
        for (; j > 0; --j) {
            unsigned h = coarse[j];
            if (cum + h >= KSEL) break;
            cum += h;
        }
        int hi = j * 32 + 31; if (hi > NBINS - 1) hi = NBINS - 1;
        int B = 0;
        for (int b = hi; b >= j * 32; --b) {
            unsigned h = hist[b];
            if (cum + h >= KSEL) { B = b; break; }
            cum += h;
        }
        sB = B; sc0 = (int)cum;   // cum = count strictly above bin B (< 50)
    }
    __syncthreads();
    int B = sB, c0 = sc0;

    // Phase 3: emit definite winners; collect boundary-bin candidates
    #pragma unroll
    for (int s = 0; s < 8; ++s) {
        int i = (t + (s >> 2) * 1024) * 4 + (s & 3);
        if (bins[s] > B) {
            unsigned pos = atomicAdd(&above_cnt, 1u);
            topk[c * KSEL + pos] = i;
        } else if (bins[s] == B) {
            unsigned j = atomicAdd(&cand_cnt, 1u);
            if (j < 2048)
                cand[j] = ((unsigned long long)keys[s] << 32) |
                          (unsigned long long)(0xFFFFFFFFu - (unsigned)i);
        }
    }
    __syncthreads();

    // Phase 4: wave 0 picks remaining (50 - c0) best boundary candidates.
    int m = KSEL - c0;
    int cb = (int)cand_cnt; if (cb > 2048) cb = 2048;
    if (t < 64) {
        for (int r = 0; r < m; ++r) {
            unsigned long long best = 0;
            for (int j = t; j < cb; j += 64) {
                unsigned long long v = cand[j];
                if (v > best) best = v;
            }
            #pragma unroll
            for (int off = 32; off; off >>= 1) {
                unsigned long long o = __shfl_xor(best, off);
                if (o > best) best = o;
            }
            if (t == 0) topk[c * KSEL + c0 + r] = (int)(0xFFFFFFFFu - (unsigned)(best & 0xFFFFFFFFull));
            for (int j = t; j < cb; j += 64)
                if (cand[j] == best) cand[j] = 0;
        }
    }
}

// ---------------------------------------------------------------------------
// Kernel 3: same-class GEMM-style loss.  Block = 32 pixels of one class.
// Thread (ktid 0..7, pxid 0..31) owns 8 k-rows x 1 pixel; dots accumulate in
// registers over all 128 channels (no shuffles in inner loop).
// Accumulates (li+lp)/NPIX straight into d_out (zeroed by topk_kernel).
// ---------------------------------------------------------------------------
__global__ void __launch_bounds__(256) loss_kernel(
        const float* __restrict__ ni, const float* __restrict__ npos,
        const float* __restrict__ nn, const int* __restrict__ topk,
        const int* __restrict__ perm, const int* __restrict__ cnt,
        float* __restrict__ out) {
    __shared__ float Sl[KPAD * SROW];   // 33792 B
    __shared__ float Xl[PXT * SROW];    // 16896 B
    __shared__ float Pl[PXT * SROW];    // 16896 B
    __shared__ float bsum[4];

    int c = blockIdx.y;
    int count = cnt[c];
    int start = blockIdx.x * PXT;
    if (start >= count) return;
    int t = threadIdx.x;

    // stage S: 4 threads per row, 32 ch each
    {
        int row = t >> 2;
        int ch0 = (t & 3) * 32;
        float* dst = &Sl[row * SROW + ch0];
        if (row < KSEL) {
            const float* src = nn + (size_t)topk[c * KSEL + row] * CCH + ch0;
            #pragma unroll
            for (int i = 0; i < 8; ++i)
                ((float4*)dst)[i] = ((const float4*)src)[i];
        } else {
            float4 z = make_float4(0.f, 0.f, 0.f, 0.f);
            #pragma unroll
            for (int i = 0; i < 8; ++i)
                ((float4*)dst)[i] = z;
        }
    }
    // stage X, P: 8 threads per pixel row, 16 ch each
    {
        int row = t >> 3;
        int slot = start + row;
        int px = perm[c * NPIX + ((slot < count) ? slot : start)];
        int ch0 = (t & 7) * 16;
        const float* sx = ni + (size_t)px * CCH + ch0;
        const float* sp = npos + (size_t)px * CCH + ch0;
        float* dx = &Xl[row * SROW + ch0];
        float* dp = &Pl[row * SROW + ch0];
        #pragma unroll
        for (int i = 0; i < 4; ++i) {
            ((float4*)dx)[i] = ((const float4*)sx)[i];
            ((float4*)dp)[i] = ((const float4*)sp)[i];
        }
    }
    __syncthreads();

    int ktid = t & 7, pxid = t >> 3;
    float acc_i[8] = {0.f, 0.f, 0.f, 0.f, 0.f, 0.f, 0.f, 0.f};
    float acc_p[8] = {0.f, 0.f, 0.f, 0.f, 0.f, 0.f, 0.f, 0.f};
    float ps = 0.f;
    const float* Xr = &Xl[pxid * SROW];
    const float* Pr = &Pl[pxid * SROW];

    #pragma unroll 2
    for (int ch = 0; ch < CCH; ch += 4) {
        float4 xv = *(const float4*)&Xr[ch];
        float4 pv = *(const float4*)&Pr[ch];
        ps += xv.x * pv.x + xv.y * pv.y + xv.z * pv.z + xv.w * pv.w;
        #pragma unroll
        for (int r = 0; r < 8; ++r) {
            float4 sv = *(const float4*)&Sl[(ktid + r * 8) * SROW + ch];
            acc_i[r] += sv.x * xv.x + sv.y * xv.y + sv.z * xv.z + sv.w * xv.w;
            acc_p[r] += sv.x * pv.x + sv.y * pv.y + sv.z * pv.z + sv.w * pv.w;
        }
    }

    float si = 0.f, spp = 0.f;
    #pragma unroll
    for (int r = 0; r < 8; ++r) {
        si  += expf(acc_i[r] * TAU_INV);
        spp += expf(acc_p[r] * TAU_INV);
    }
    // reduce over the 8 ktid lanes (consecutive within the wave)
    #pragma unroll
    for (int off = 1; off < 8; off <<= 1) {
        si  += __shfl_xor(si, off);
        spp += __shfl_xor(spp, off);
    }

    float v = 0.f;
    if (ktid == 0 && (start + pxid) < count) {
        si  -= (float)(KPAD - KSEL);   // remove exp(0)=1 of the 14 zero rows
        spp -= (float)(KPAD - KSEL);
        float nom = expf(ps * TAU_INV);
        float li = -logf(nom / (si + nom + EPSL));
        float lp = -logf(nom / (spp + nom + EPSL));
        v = (li + lp) * (1.0f / (float)NPIX);
    }
    // sum the 8 per-pixel leaders in each wave, then block, then global
    v += __shfl_xor(v, 8);
    v += __shfl_xor(v, 16);
    v += __shfl_xor(v, 32);
    int w = t >> 6;
    if ((t & 63) == 0) bsum[w] = v;
    __syncthreads();
    if (t == 0) atomicAdd(out, bsum[0] + bsum[1] + bsum[2] + bsum[3]);
}

// ---------------------------------------------------------------------------
extern "C" void kernel_launch(void* const* d_in, const int* in_sizes, int n_in,
                              void* d_out, int out_size, void* d_ws, size_t ws_size,
                              hipStream_t stream) {
    const float* input      = (const float*)d_in[0];
    const float* positive   = (const float*)d_in[1];
    const float* negative   = (const float*)d_in[2];
    const float* in_logits  = (const float*)d_in[3];
    const float* neg_logits = (const float*)d_in[4];
    float* out = (float*)d_out;

    float* ws  = (float*)d_ws;
    float* ni  = ws;                               // [N*C]
    float* np_ = ws + 1048576;                     // [N*C]
    float* nn  = ws + 2097152;                     // [N*C]
    int*   seg_in   = (int*)(ws + 3145728);        // [N]
    int*   seg_neg  = seg_in + NPIX;               // [N]
    float* neg_prob = (float*)(seg_neg + NPIX);    // [N]
    int*   topk     = (int*)(neg_prob + NPIX);     // [4*50] (pad 256)
    int*   cnt      = topk + 256;                  // [4] (pad 64)
    int*   perm     = cnt + 64;                    // [4*N]

    mega_kernel<<<392, 256, 0, stream>>>(input, positive, negative,
                                         in_logits, neg_logits,
                                         ni, np_, nn, seg_in, seg_neg, neg_prob);
    topk_kernel<<<NCLS, 1024, 0, stream>>>(seg_in, seg_neg, neg_prob,
                                           topk, perm, cnt, out);
    dim3 lgrid(NPIX / PXT, NCLS);
    loss_kernel<<<lgrid, 256, 0, stream>>>(ni, np_, nn, topk, perm, cnt, out);
}